// Round 3
// baseline (391.283 us; speedup 1.0000x reference)
//
#include <hip/hip_runtime.h>
#include <math.h>

#define NB 128
#define NT 2048
#define ND 256
#define NE 32
#define NL 8
#define NP 168
#define SCL 0.0625f   // 1/sqrt(256)

// workspace float offsets
#define OFF_QK   0          // 8*256      qkmat[l][d] (scale folded)
#define OFF_LATQ 2048       // 8*256      latents@w_lat_q
#define OFF_WVO  4096       // 65536      w_ctx_v @ w_lat_out
#define OFF_WSO1 69632      // 65536      w_step_out @ gate_w1[256:]
#define OFF_G0   135168     // 168*256    step_base@gate_w1[:256]+b1
#define OFF_Q2S  178176     // 168*256    step_base@w_step_q * scale
#define OFF_AV   221184     // 128*8*8*256 partial weighted sums
#define OFF_DEN  2318336    // 128*8*8    partial exp sums
#define OFF_K2   2326528    // 128*8*256
#define OFF_V2   2588672    // 128*8*256

typedef __attribute__((ext_vector_type(8))) short short8b;
typedef __attribute__((ext_vector_type(4))) float f32x4;

static __device__ __forceinline__ unsigned short f2bf(float f){
  unsigned u = __float_as_uint(f);
  u += 0x7fffu + ((u >> 16) & 1u);
  return (unsigned short)(u >> 16);
}

static __device__ __forceinline__ short8b pack8(float4 lo, float4 hi){
  short8b r;
  r[0]=(short)f2bf(lo.x); r[1]=(short)f2bf(lo.y); r[2]=(short)f2bf(lo.z); r[3]=(short)f2bf(lo.w);
  r[4]=(short)f2bf(hi.x); r[5]=(short)f2bf(hi.y); r[6]=(short)f2bf(hi.z); r[7]=(short)f2bf(hi.w);
  return r;
}

// ---------------- precompute 1: Wvo, Wso1, G0/q2s, latq ----------------
__global__ __launch_bounds__(256) void pre1(const float* __restrict__ latents,
    const float* __restrict__ wlq, const float* __restrict__ wcv,
    const float* __restrict__ wlo, const float* __restrict__ wso,
    const float* __restrict__ gw1, const float* __restrict__ gb1,
    const float* __restrict__ qpos, const float* __restrict__ lemb,
    const float* __restrict__ wsq, float* __restrict__ ws)
{
  int bid = blockIdx.x, tid = threadIdx.x;
  if (bid < 256){                 // W_vo row d = bid
    const float* a = wcv + bid*ND;
    float acc = 0.f;
    #pragma unroll 8
    for (int k=0;k<ND;k++) acc += a[k]*wlo[k*ND+tid];
    ws[OFF_WVO + bid*ND + tid] = acc;
  } else if (bid < 512){          // W_so1 row i = bid-256
    int i = bid-256;
    const float* a = wso + i*ND;
    float acc = 0.f;
    #pragma unroll 8
    for (int k=0;k<ND;k++) acc += a[k]*gw1[(ND+k)*ND+tid];
    ws[OFF_WSO1 + i*ND + tid] = acc;
  } else if (bid < 512+NP){       // G0 / q2s row p = bid-512
    int p = bid-512;
    float ag = gb1[tid], aq = 0.f;
    #pragma unroll 4
    for (int j=0;j<ND;j++){
      float sb = qpos[p*ND+j] + lemb[NP*ND+j];
      ag += sb*gw1[j*ND+tid];
      aq += sb*wsq[j*ND+tid];
    }
    ws[OFF_G0  + p*ND + tid] = ag;
    ws[OFF_Q2S + p*ND + tid] = aq*SCL;
  } else {                        // latq row l
    int l = bid-(512+NP);
    float acc = 0.f;
    #pragma unroll 8
    for (int m=0;m<ND;m++) acc += latents[l*ND+m]*wlq[m*ND+tid];
    ws[OFF_LATQ + l*ND + tid] = acc;
  }
}

// ---------------- precompute 2: qkmat[l][d] = (latq @ Wck^T)*scale ----------------
__global__ __launch_bounds__(256) void pre2(const float* __restrict__ wck, float* __restrict__ ws)
{
  int d = blockIdx.x, tid = threadIdx.x;
  float wk = wck[d*ND + tid];
  float part[NL];
  #pragma unroll
  for (int l=0;l<NL;l++) part[l] = ws[OFF_LATQ + l*ND + tid]*wk;
  #pragma unroll
  for (int m=1;m<64;m<<=1){
    #pragma unroll
    for (int l=0;l<NL;l++) part[l] += __shfl_xor(part[l], m);
  }
  __shared__ float red[4][NL];
  if ((tid&63)==0){
    #pragma unroll
    for (int l=0;l<NL;l++) red[tid>>6][l] = part[l];
  }
  __syncthreads();
  if (tid < NL){
    float s = red[0][tid]+red[1][tid]+red[2][tid]+red[3][tid];
    ws[OFF_QK + tid*ND + d] = s*SCL;
  }
}

// ---------------- kernel A: flash attn1 partials, single HBM pass ----------------
// grid = 128*8 ; block 256. Register-prefetched across subs: next sub's loads
// are issued before this sub's compute, staying in flight across both barriers.
__global__ __launch_bounds__(256) void kA(const float* __restrict__ ctx, float* __restrict__ ws)
{
  __shared__ float ctile[64*256];   // 64KB swizzled
  __shared__ float efull[256*8];    // 8KB e[t][l]

  int bid = blockIdx.x;
  int b = bid >> 3, sp = bid & 7;
  int tid = threadIdx.x;
  int wv = tid >> 6, lane = tid & 63;
  int c = lane & 15, g = lane >> 4;
  int dq = lane;

  short8b afrag[8];
  if (c < NL){
    const float* qk = ws + OFF_QK + c*ND + g*8;
    #pragma unroll
    for (int kk=0;kk<8;kk++){
      float4 lo = *(const float4*)(qk + kk*32);
      float4 hi = *(const float4*)(qk + kk*32 + 4);
      afrag[kk] = pack8(lo, hi);
    }
  } else {
    short8b z;
    #pragma unroll
    for (int j=0;j<8;j++) z[j] = 0;
    #pragma unroll
    for (int kk=0;kk<8;kk++) afrag[kk] = z;
  }

  float av[8][4];
  #pragma unroll
  for (int l=0;l<8;l++){
    #pragma unroll
    for (int j=0;j<4;j++) av[l][j] = 0.f;
  }

  int rr = wv*16 + c, r7 = rr & 7;
  float* crow = ctile + rr*256;
  const float* cbase = ctx + ((size_t)(b*NT + sp*256 + rr))*ND + g*8;

  float4 A0[8], B0[8], A1[8], B1[8];
  #pragma unroll
  for (int kk=0;kk<8;kk++){
    A0[kk] = *(const float4*)(cbase + kk*32);
    B0[kk] = *(const float4*)(cbase + kk*32 + 4);
  }

#define KA_SUB(SUBI, CA, CB, NA, NBv, PF)                                        \
  do {                                                                            \
    if (PF){                                                                      \
      const float* np_ = cbase + (size_t)(SUBI+1)*64*ND;                          \
      _Pragma("unroll")                                                           \
      for (int kk=0;kk<8;kk++){                                                   \
        NA[kk]  = *(const float4*)(np_ + kk*32);                                  \
        NBv[kk] = *(const float4*)(np_ + kk*32 + 4);                              \
      }                                                                           \
    }                                                                             \
    _Pragma("unroll")                                                             \
    for (int kk=0;kk<8;kk++){                                                     \
      int slo = 2*g + 8*kk;                                                       \
      *(float4*)(crow + (((slo  ) ^ r7)<<2)) = CA[kk];                            \
      *(float4*)(crow + (((slo+1) ^ r7)<<2)) = CB[kk];                            \
    }                                                                             \
    f32x4 acc = {0.f,0.f,0.f,0.f};                                                \
    _Pragma("unroll")                                                             \
    for (int kk=0;kk<8;kk++)                                                      \
      acc = __builtin_amdgcn_mfma_f32_16x16x32_bf16(afrag[kk], pack8(CA[kk],CB[kk]), acc, 0, 0, 0); \
    if (g < 2){                                                                   \
      float4 ev = make_float4(__expf(acc[0]),__expf(acc[1]),__expf(acc[2]),__expf(acc[3])); \
      *(float4*)&efull[((SUBI)*64 + rr)*8 + g*4] = ev;                            \
    }                                                                             \
    __syncthreads();                                                              \
    _Pragma("unroll")                                                             \
    for (int i=0;i<16;i++){                                                       \
      int tl = wv*16 + i;                                                         \
      float4 c4 = *(const float4*)(ctile + tl*256 + ((dq ^ (tl&7))<<2));          \
      const float* ep = efull + ((SUBI)*64 + tl)*8;                               \
      float4 e0 = *(const float4*)ep;                                             \
      float4 e1 = *(const float4*)(ep+4);                                         \
      av[0][0]+=e0.x*c4.x; av[0][1]+=e0.x*c4.y; av[0][2]+=e0.x*c4.z; av[0][3]+=e0.x*c4.w; \
      av[1][0]+=e0.y*c4.x; av[1][1]+=e0.y*c4.y; av[1][2]+=e0.y*c4.z; av[1][3]+=e0.y*c4.w; \
      av[2][0]+=e0.z*c4.x; av[2][1]+=e0.z*c4.y; av[2][2]+=e0.z*c4.z; av[2][3]+=e0.z*c4.w; \
      av[3][0]+=e0.w*c4.x; av[3][1]+=e0.w*c4.y; av[3][2]+=e0.w*c4.z; av[3][3]+=e0.w*c4.w; \
      av[4][0]+=e1.x*c4.x; av[4][1]+=e1.x*c4.y; av[4][2]+=e1.x*c4.z; av[4][3]+=e1.x*c4.w; \
      av[5][0]+=e1.y*c4.x; av[5][1]+=e1.y*c4.y; av[5][2]+=e1.y*c4.z; av[5][3]+=e1.y*c4.w; \
      av[6][0]+=e1.z*c4.x; av[6][1]+=e1.z*c4.y; av[6][2]+=e1.z*c4.z; av[6][3]+=e1.z*c4.w; \
      av[7][0]+=e1.w*c4.x; av[7][1]+=e1.w*c4.y; av[7][2]+=e1.w*c4.z; av[7][3]+=e1.w*c4.w; \
    }                                                                             \
    __syncthreads();                                                              \
  } while(0)

  KA_SUB(0, A0, B0, A1, B1, 1);
  KA_SUB(1, A1, B1, A0, B0, 1);
  KA_SUB(2, A0, B0, A1, B1, 1);
  KA_SUB(3, A1, B1, A0, B0, 0);
#undef KA_SUB

  // cross-group reduce of av via LDS (alias ctile; reads done)
  float* red = ctile;  // [l][tq][dq][4]
  #pragma unroll
  for (int l=0;l<8;l++)
    *(float4*)(red + (((l*4 + wv)*64 + dq)<<2)) = make_float4(av[l][0],av[l][1],av[l][2],av[l][3]);

  // den: wave 0 sums e over all 256 rows
  if (wv == 0){
    float dpart[8];
    #pragma unroll
    for (int l=0;l<8;l++) dpart[l] = 0.f;
    #pragma unroll
    for (int q=0;q<4;q++){
      const float* ep = efull + (q*64 + lane)*8;
      float4 e0 = *(const float4*)ep;
      float4 e1 = *(const float4*)(ep+4);
      dpart[0]+=e0.x; dpart[1]+=e0.y; dpart[2]+=e0.z; dpart[3]+=e0.w;
      dpart[4]+=e1.x; dpart[5]+=e1.y; dpart[6]+=e1.z; dpart[7]+=e1.w;
    }
    #pragma unroll
    for (int m=1;m<64;m<<=1){
      #pragma unroll
      for (int l=0;l<8;l++) dpart[l] += __shfl_xor(dpart[l], m);
    }
    if (lane == 0){
      #pragma unroll
      for (int l=0;l<8;l++) ws[OFF_DEN + bid*8 + l] = dpart[l];
    }
  }
  __syncthreads();

  #pragma unroll
  for (int rep=0; rep<2; ++rep){
    int lidx = tid + rep*256;
    int l = lidx >> 6, d2 = lidx & 63;
    float4 s0 = *(const float4*)(red + (((l*4 + 0)*64 + d2)<<2));
    float4 s1 = *(const float4*)(red + (((l*4 + 1)*64 + d2)<<2));
    float4 s2 = *(const float4*)(red + (((l*4 + 2)*64 + d2)<<2));
    float4 s3 = *(const float4*)(red + (((l*4 + 3)*64 + d2)<<2));
    float4 o;
    o.x = s0.x+s1.x+s2.x+s3.x;
    o.y = s0.y+s1.y+s2.y+s3.y;
    o.z = s0.z+s1.z+s2.z+s3.z;
    o.w = s0.w+s1.w+s2.w+s3.w;
    *(float4*)&ws[OFF_AV + ((size_t)(bid*8 + l))*ND + d2*4] = o;
  }
}

// ---------------- kernel B1: combine + lat_ctx + k2/v2 ----------------
// grid = 256: block (b, half). Both halves compute avn+lat; half 0 writes K2,
// half 1 writes V2 (splits the serial tail, doubles GPU utilization).
__global__ __launch_bounds__(256) void kB1(const float* __restrict__ wlk,
                                           const float* __restrict__ wlv,
                                           float* __restrict__ ws)
{
  int bid = blockIdx.x;
  int b = bid >> 1, half = bid & 1;
  int d = threadIdx.x;
  __shared__ float avnT[256][8];
  __shared__ float latT[256][8];

  float dent[8];
  #pragma unroll
  for (int l=0;l<8;l++){
    float s = 0.f;
    #pragma unroll
    for (int sp=0;sp<8;sp++) s += ws[OFF_DEN + (b*8+sp)*8 + l];
    dent[l] = s;
  }
  float av8[8];
  #pragma unroll
  for (int l=0;l<8;l++){
    float s = 0.f;
    #pragma unroll
    for (int sp=0;sp<8;sp++) s += ws[OFF_AV + ((size_t)((b*8+sp)*8 + l))*ND + d];
    av8[l] = s / dent[l];
  }
  *(float4*)&avnT[d][0] = make_float4(av8[0],av8[1],av8[2],av8[3]);
  *(float4*)&avnT[d][4] = make_float4(av8[4],av8[5],av8[6],av8[7]);
  __syncthreads();

  float lc[8];
  #pragma unroll
  for (int l=0;l<8;l++) lc[l] = 0.f;
  #pragma unroll 8
  for (int dd=0;dd<ND;dd++){
    float w = ws[OFF_WVO + dd*ND + d];
    float4 a0 = *(const float4*)&avnT[dd][0];
    float4 a1 = *(const float4*)&avnT[dd][4];
    lc[0]+=a0.x*w; lc[1]+=a0.y*w; lc[2]+=a0.z*w; lc[3]+=a0.w*w;
    lc[4]+=a1.x*w; lc[5]+=a1.y*w; lc[6]+=a1.z*w; lc[7]+=a1.w*w;
  }
  *(float4*)&latT[d][0] = make_float4(lc[0],lc[1],lc[2],lc[3]);
  *(float4*)&latT[d][4] = make_float4(lc[4],lc[5],lc[6],lc[7]);
  __syncthreads();

  const float* w3 = half ? wlv : wlk;
  float o8[8];
  #pragma unroll
  for (int l=0;l<8;l++) o8[l] = 0.f;
  #pragma unroll 8
  for (int dd=0;dd<ND;dd++){
    float w = w3[dd*ND + d];
    float4 a0 = *(const float4*)&latT[dd][0];
    float4 a1 = *(const float4*)&latT[dd][4];
    o8[0]+=a0.x*w; o8[1]+=a0.y*w; o8[2]+=a0.z*w; o8[3]+=a0.w*w;
    o8[4]+=a1.x*w; o8[5]+=a1.y*w; o8[6]+=a1.z*w; o8[7]+=a1.w*w;
  }
  size_t obase = (half ? OFF_V2 : OFF_K2) + (size_t)b*8*ND + d;
  #pragma unroll
  for (int l=0;l<8;l++) ws[obase + l*ND] = o8[l];
}

// ---------------- kernel B2: attn2 + gate + top2 + output ----------------
__global__ __launch_bounds__(256) void kB2(const float* __restrict__ ws,
    const float* __restrict__ gw2, const float* __restrict__ gb2,
    const float* __restrict__ qe, float* __restrict__ out)
{
  int bid = blockIdx.x;
  int b = bid / 6, p0 = (bid % 6)*28;
  int tid = threadIdx.x;

  __shared__ float q2h[28][260];
  __shared__ float k2s[8][260];
  __shared__ float aos[28][260];
  __shared__ float wexp[28][8];
  __shared__ float lg[28][33];
  __shared__ float4 sel[28];

  // S0: stage (vectorized)
  #pragma unroll
  for (int i=0;i<7;i++){
    int idx = tid + i*256;           // float4 index over 28*64
    int r = idx >> 6, c4 = idx & 63;
    *(float4*)&q2h[r][c4*4] = *(const float4*)&ws[OFF_Q2S + (p0+r)*ND + c4*4];
  }
  #pragma unroll
  for (int i=0;i<2;i++){
    int idx = tid + i*256;           // float4 index over 8*64
    int l = idx >> 6, c4 = idx & 63;
    *(float4*)&k2s[l][c4*4] = *(const float4*)&ws[OFF_K2 + (b*8+l)*ND + c4*4];
  }
  float v2r[8];
  #pragma unroll
  for (int l=0;l<8;l++) v2r[l] = ws[OFF_V2 + (b*8+l)*ND + tid];
  __syncthreads();

  // S1: s2 dots + softmax over L=8
  {
    int pp = tid >> 3, l1 = tid & 7;
    if (pp < 28){
      float s2 = 0.f;
      #pragma unroll 8
      for (int i=0;i<64;i++){
        float4 qa = *(const float4*)&q2h[pp][4*i];
        float4 kb = *(const float4*)&k2s[l1][4*i];
        s2 += qa.x*kb.x + qa.y*kb.y + qa.z*kb.z + qa.w*kb.w;
      }
      float e2 = __expf(s2);
      float den = e2;
      den += __shfl_xor(den,1); den += __shfl_xor(den,2); den += __shfl_xor(den,4);
      wexp[pp][l1] = e2/den;
    }
  }
  __syncthreads();

  // S2: ao[p][i=tid] = sum_l w[p][l]*v2[l][i]
  for (int p=0;p<28;p++){
    float4 w0 = *(const float4*)&wexp[p][0];
    float4 w1v = *(const float4*)&wexp[p][4];
    float a = w0.x*v2r[0]+w0.y*v2r[1]+w0.z*v2r[2]+w0.w*v2r[3]
            + w1v.x*v2r[4]+w1v.y*v2r[5]+w1v.z*v2r[6]+w1v.w*v2r[7];
    aos[p][tid] = a;
  }
  __syncthreads();

  // S3: x = G0 + ao @ W_so1 ; h = gelu(x)
  {
    int cq = tid & 63, pg = tid >> 6;
    int c0 = cq*4;
    float xacc[7][4];
    #pragma unroll
    for (int r7=0;r7<7;r7++){
      float4 g0 = *(const float4*)&ws[OFF_G0 + (p0+pg*7+r7)*ND + c0];
      xacc[r7][0]=g0.x; xacc[r7][1]=g0.y; xacc[r7][2]=g0.z; xacc[r7][3]=g0.w;
    }
    for (int i0=0;i0<ND;i0+=4){
      float4 w0 = *(const float4*)&ws[OFF_WSO1 + (i0+0)*ND + c0];
      float4 w1 = *(const float4*)&ws[OFF_WSO1 + (i0+1)*ND + c0];
      float4 w2 = *(const float4*)&ws[OFF_WSO1 + (i0+2)*ND + c0];
      float4 w3 = *(const float4*)&ws[OFF_WSO1 + (i0+3)*ND + c0];
      #pragma unroll
      for (int r7=0;r7<7;r7++){
        float4 a4 = *(const float4*)&aos[pg*7+r7][i0];
        xacc[r7][0] += a4.x*w0.x + a4.y*w1.x + a4.z*w2.x + a4.w*w3.x;
        xacc[r7][1] += a4.x*w0.y + a4.y*w1.y + a4.z*w2.y + a4.w*w3.y;
        xacc[r7][2] += a4.x*w0.z + a4.y*w1.z + a4.z*w2.z + a4.w*w3.z;
        xacc[r7][3] += a4.x*w0.w + a4.y*w1.w + a4.z*w2.w + a4.w*w3.w;
      }
    }
    __syncthreads();
    #pragma unroll
    for (int r7=0;r7<7;r7++){
      float4 h4;
      float x0=xacc[r7][0], x1=xacc[r7][1], x2=xacc[r7][2], x3=xacc[r7][3];
      h4.x = 0.5f*x0*(1.f+erff(x0*0.70710678118654752f));
      h4.y = 0.5f*x1*(1.f+erff(x1*0.70710678118654752f));
      h4.z = 0.5f*x2*(1.f+erff(x2*0.70710678118654752f));
      h4.w = 0.5f*x3*(1.f+erff(x3*0.70710678118654752f));
      *(float4*)&q2h[pg*7+r7][c0] = h4;
    }
  }
  __syncthreads();

  // S4: logits = h @ gw2 + b2
  {
    int e = tid & 31, pq = tid >> 5;
    if (pq < 7){
      float b2v = gb2[e];
      float a0=b2v, a1=b2v, a2=b2v, a3=b2v;
      for (int cc=0;cc<ND;cc+=4){
        float w20 = gw2[(cc+0)*NE + e];
        float w21 = gw2[(cc+1)*NE + e];
        float w22 = gw2[(cc+2)*NE + e];
        float w23 = gw2[(cc+3)*NE + e];
        float4 h0 = *(const float4*)&q2h[pq*4+0][cc];
        float4 h1 = *(const float4*)&q2h[pq*4+1][cc];
        float4 h2 = *(const float4*)&q2h[pq*4+2][cc];
        float4 h3 = *(const float4*)&q2h[pq*4+3][cc];
        a0 += h0.x*w20 + h0.y*w21 + h0.z*w22 + h0.w*w23;
        a1 += h1.x*w20 + h1.y*w21 + h1.z*w22 + h1.w*w23;
        a2 += h2.x*w20 + h2.y*w21 + h2.z*w22 + h2.w*w23;
        a3 += h3.x*w20 + h3.y*w21 + h3.z*w22 + h3.w*w23;
      }
      lg[pq*4+0][e] = a0;
      lg[pq*4+1][e] = a1;
      lg[pq*4+2][e] = a2;
      lg[pq*4+3][e] = a3;
    }
  }
  __syncthreads();

  // S5: top-2 + masked softmax weights
  if (tid < 28){
    float m1 = -1e30f, m2 = -1e30f;
    int e1 = 0, ee2 = 0;
    for (int e3=0;e3<NE;e3++){
      float v = lg[tid][e3];
      if (v > m1){ m2 = m1; ee2 = e1; m1 = v; e1 = e3; }
      else if (v > m2){ m2 = v; ee2 = e3; }
    }
    float z = __expf(m2 - m1);
    float inv = 1.f/(1.f+z);
    sel[tid] = make_float4(__int_as_float(e1), __int_as_float(ee2), inv, z*inv);
  }
  __syncthreads();

  // S6: output mix
  for (int p=0;p<28;p++){
    float4 s = sel[p];
    int e1 = __float_as_int(s.x), ee2 = __float_as_int(s.y);
    float q1v = qe[((size_t)e1*NP + (p0+p))*ND + tid];
    float q2v = qe[((size_t)ee2*NP + (p0+p))*ND + tid];
    out[((size_t)b*NP + (p0+p))*ND + tid] = s.z*q1v + s.w*q2v;
  }
}

extern "C" void kernel_launch(void* const* d_in, const int* in_sizes, int n_in,
                              void* d_out, int out_size, void* d_ws, size_t ws_size,
                              hipStream_t stream)
{
  const float* ctx  = (const float*)d_in[0];
  const float* qe   = (const float*)d_in[1];
  const float* qpos = (const float*)d_in[2];
  const float* lemb = (const float*)d_in[3];
  const float* lat  = (const float*)d_in[4];
  const float* wlq  = (const float*)d_in[5];
  const float* wck  = (const float*)d_in[6];
  const float* wcv  = (const float*)d_in[7];
  const float* wlo  = (const float*)d_in[8];
  const float* wsq  = (const float*)d_in[9];
  const float* wlk  = (const float*)d_in[10];
  const float* wlv  = (const float*)d_in[11];
  const float* wso  = (const float*)d_in[12];
  const float* gw1  = (const float*)d_in[13];
  const float* gb1  = (const float*)d_in[14];
  const float* gw2  = (const float*)d_in[15];
  const float* gb2  = (const float*)d_in[16];
  float* out = (float*)d_out;
  float* ws  = (float*)d_ws;

  pre1<<<512+NP+NL, 256, 0, stream>>>(lat, wlq, wcv, wlo, wso, gw1, gb1, qpos, lemb, wsq, ws);
  pre2<<<256, 256, 0, stream>>>(wck, ws);
  kA  <<<NB*8, 256, 0, stream>>>(ctx, ws);
  kB1 <<<NB*2, 256, 0, stream>>>(wlk, wlv, ws);
  kB2 <<<NB*6, 256, 0, stream>>>(ws, gw2, gb2, qe, out);
}

// Round 4
// 154.010 us; speedup vs baseline: 2.5406x; 2.5406x over previous
//
#include <hip/hip_runtime.h>
#include <math.h>

#define NB 128
#define NT 2048
#define ND 256
#define NE 32
#define NL 8
#define NP 168
#define SCL 0.0625f   // 1/sqrt(256)

// workspace float offsets
#define OFF_QK   0          // 8*256      qkmat[l][d] (scale folded)
#define OFF_LATQ 2048       // 8*256      latents@w_lat_q
#define OFF_WVO  4096       // 65536      w_ctx_v @ w_lat_out
#define OFF_WSO1 69632      // 65536      w_step_out @ gate_w1[256:]
#define OFF_WVW  135168     // 65536      wlv @ WSO1
#define OFF_G0   200704     // 168*256    step_base@gate_w1[:256]+b1
#define OFF_Q2S  243712     // 168*256    step_base@w_step_q * scale
#define OFF_AV   286720     // 128*8*8*256 partial weighted sums
#define OFF_DEN  2383872    // 128*8*8    partial exp sums
#define OFF_K2   2392064    // 128*8*256
#define OFF_VW   2654208    // 128*8*256  (lat @ WVW) = v2 @ WSO1

typedef __attribute__((ext_vector_type(8))) short short8b;
typedef __attribute__((ext_vector_type(4))) float f32x4;

static __device__ __forceinline__ unsigned short f2bf(float f){
  unsigned u = __float_as_uint(f);
  u += 0x7fffu + ((u >> 16) & 1u);
  return (unsigned short)(u >> 16);
}

static __device__ __forceinline__ short8b pack8(float4 lo, float4 hi){
  short8b r;
  r[0]=(short)f2bf(lo.x); r[1]=(short)f2bf(lo.y); r[2]=(short)f2bf(lo.z); r[3]=(short)f2bf(lo.w);
  r[4]=(short)f2bf(hi.x); r[5]=(short)f2bf(hi.y); r[6]=(short)f2bf(hi.z); r[7]=(short)f2bf(hi.w);
  return r;
}

// ---------------- precompute 1: Wvo, Wso1, G0/q2s, latq ----------------
__global__ __launch_bounds__(256) void pre1(const float* __restrict__ latents,
    const float* __restrict__ wlq, const float* __restrict__ wcv,
    const float* __restrict__ wlo, const float* __restrict__ wso,
    const float* __restrict__ gw1, const float* __restrict__ gb1,
    const float* __restrict__ qpos, const float* __restrict__ lemb,
    const float* __restrict__ wsq, float* __restrict__ ws)
{
  int bid = blockIdx.x, tid = threadIdx.x;
  if (bid < 256){                 // W_vo row d = bid
    const float* a = wcv + bid*ND;
    float acc = 0.f;
    #pragma unroll 8
    for (int k=0;k<ND;k++) acc += a[k]*wlo[k*ND+tid];
    ws[OFF_WVO + bid*ND + tid] = acc;
  } else if (bid < 512){          // W_so1 row i = bid-256
    int i = bid-256;
    const float* a = wso + i*ND;
    float acc = 0.f;
    #pragma unroll 8
    for (int k=0;k<ND;k++) acc += a[k]*gw1[(ND+k)*ND+tid];
    ws[OFF_WSO1 + i*ND + tid] = acc;
  } else if (bid < 512+NP){       // G0 / q2s row p = bid-512
    int p = bid-512;
    float ag = gb1[tid], aq = 0.f;
    #pragma unroll 4
    for (int j=0;j<ND;j++){
      float sb = qpos[p*ND+j] + lemb[NP*ND+j];
      ag += sb*gw1[j*ND+tid];
      aq += sb*wsq[j*ND+tid];
    }
    ws[OFF_G0  + p*ND + tid] = ag;
    ws[OFF_Q2S + p*ND + tid] = aq*SCL;
  } else {                        // latq row l
    int l = bid-(512+NP);
    float acc = 0.f;
    #pragma unroll 8
    for (int m=0;m<ND;m++) acc += latents[l*ND+m]*wlq[m*ND+tid];
    ws[OFF_LATQ + l*ND + tid] = acc;
  }
}

// ---------------- precompute 2: qkmat + WVW = wlv @ WSO1 ----------------
__global__ __launch_bounds__(256) void pre2(const float* __restrict__ wck,
                                            const float* __restrict__ wlv,
                                            float* __restrict__ ws)
{
  int bid = blockIdx.x, tid = threadIdx.x;
  if (bid < 256){
    int d = bid;
    float wk = wck[d*ND + tid];
    float part[NL];
    #pragma unroll
    for (int l=0;l<NL;l++) part[l] = ws[OFF_LATQ + l*ND + tid]*wk;
    #pragma unroll
    for (int m=1;m<64;m<<=1){
      #pragma unroll
      for (int l=0;l<NL;l++) part[l] += __shfl_xor(part[l], m);
    }
    __shared__ float red[4][NL];
    if ((tid&63)==0){
      #pragma unroll
      for (int l=0;l<NL;l++) red[tid>>6][l] = part[l];
    }
    __syncthreads();
    if (tid < NL){
      float s = red[0][tid]+red[1][tid]+red[2][tid]+red[3][tid];
      ws[OFF_QK + tid*ND + d] = s*SCL;
    }
  } else {
    int dd = bid - 256;
    const float* a = wlv + dd*ND;
    float acc = 0.f;
    #pragma unroll 8
    for (int k=0;k<ND;k++) acc += a[k]*ws[OFF_WSO1 + k*ND + tid];
    ws[OFF_WVW + dd*ND + tid] = acc;
  }
}

// ---------------- kernel A: flash attn1 partials, single HBM pass (R2 version) ----
__global__ __launch_bounds__(256) void kA(const float* __restrict__ ctx, float* __restrict__ ws)
{
  __shared__ float ctile[64*256];   // 64KB: rows 0..63, swizzled slots
  __shared__ float efull[256*8];    // 8KB: e[t_local][l]

  int bid = blockIdx.x;
  int b = bid >> 3, sp = bid & 7;
  int tid = threadIdx.x;
  int wv = tid >> 6, lane = tid & 63;
  int c = lane & 15, g = lane >> 4;
  int dq = lane;

  short8b afrag[8];
  if (c < NL){
    const float* qk = ws + OFF_QK + c*ND + g*8;
    #pragma unroll
    for (int kk=0;kk<8;kk++){
      float4 lo = *(const float4*)(qk + kk*32);
      float4 hi = *(const float4*)(qk + kk*32 + 4);
      afrag[kk] = pack8(lo, hi);
    }
  } else {
    short8b z;
    #pragma unroll
    for (int j=0;j<8;j++) z[j] = 0;
    #pragma unroll
    for (int kk=0;kk<8;kk++) afrag[kk] = z;
  }

  float av[8][4];
  #pragma unroll
  for (int l=0;l<8;l++){
    #pragma unroll
    for (int j=0;j<4;j++) av[l][j] = 0.f;
  }

  const int T0 = sp*256;
  #pragma unroll 1
  for (int sub=0; sub<4; ++sub){
    int rr = wv*16 + c;
    int r7 = rr & 7;
    const float* cp = ctx + ((size_t)(b*NT + T0 + sub*64 + rr))*ND + g*8;
    float4 lo[8], hi[8];
    #pragma unroll
    for (int kk=0;kk<8;kk++){
      lo[kk] = *(const float4*)(cp + kk*32);
      hi[kk] = *(const float4*)(cp + kk*32 + 4);
    }
    float* crow = ctile + rr*256;
    #pragma unroll
    for (int kk=0;kk<8;kk++){
      int slo = 2*g + 8*kk;
      *(float4*)(crow + (((slo  ) ^ r7)<<2)) = lo[kk];
      *(float4*)(crow + (((slo+1) ^ r7)<<2)) = hi[kk];
    }
    f32x4 acc = {0.f,0.f,0.f,0.f};
    #pragma unroll
    for (int kk=0;kk<8;kk++)
      acc = __builtin_amdgcn_mfma_f32_16x16x32_bf16(afrag[kk], pack8(lo[kk],hi[kk]), acc, 0, 0, 0);
    if (g < 2){
      float4 ev = make_float4(__expf(acc[0]),__expf(acc[1]),__expf(acc[2]),__expf(acc[3]));
      *(float4*)&efull[(sub*64 + rr)*8 + g*4] = ev;
    }
    __syncthreads();
    #pragma unroll
    for (int i=0;i<16;i++){
      int tl = wv*16 + i;
      float4 c4 = *(const float4*)(ctile + tl*256 + ((dq ^ (tl&7))<<2));
      const float* ep = efull + (sub*64 + tl)*8;
      float4 e0 = *(const float4*)ep;
      float4 e1 = *(const float4*)(ep+4);
      float e8[8];
      e8[0]=e0.x; e8[1]=e0.y; e8[2]=e0.z; e8[3]=e0.w;
      e8[4]=e1.x; e8[5]=e1.y; e8[6]=e1.z; e8[7]=e1.w;
      #pragma unroll
      for (int l=0;l<8;l++){
        av[l][0] += e8[l]*c4.x;
        av[l][1] += e8[l]*c4.y;
        av[l][2] += e8[l]*c4.z;
        av[l][3] += e8[l]*c4.w;
      }
    }
    __syncthreads();
  }

  float* red = ctile;  // [l][tq][dq][4]
  #pragma unroll
  for (int l=0;l<8;l++)
    *(float4*)(red + (((l*4 + wv)*64 + dq)<<2)) = make_float4(av[l][0],av[l][1],av[l][2],av[l][3]);

  if (wv == 0){
    float dpart[8];
    #pragma unroll
    for (int l=0;l<8;l++) dpart[l] = 0.f;
    #pragma unroll
    for (int q=0;q<4;q++){
      const float* ep = efull + (q*64 + lane)*8;
      float4 e0 = *(const float4*)ep;
      float4 e1 = *(const float4*)(ep+4);
      dpart[0]+=e0.x; dpart[1]+=e0.y; dpart[2]+=e0.z; dpart[3]+=e0.w;
      dpart[4]+=e1.x; dpart[5]+=e1.y; dpart[6]+=e1.z; dpart[7]+=e1.w;
    }
    #pragma unroll
    for (int m=1;m<64;m<<=1){
      #pragma unroll
      for (int l=0;l<8;l++) dpart[l] += __shfl_xor(dpart[l], m);
    }
    if (lane == 0){
      #pragma unroll
      for (int l=0;l<8;l++) ws[OFF_DEN + bid*8 + l] = dpart[l];
    }
  }
  __syncthreads();

  #pragma unroll
  for (int rep=0; rep<2; ++rep){
    int lidx = tid + rep*256;
    int l = lidx >> 6, d2 = lidx & 63;
    float4 s0 = *(const float4*)(red + (((l*4 + 0)*64 + d2)<<2));
    float4 s1 = *(const float4*)(red + (((l*4 + 1)*64 + d2)<<2));
    float4 s2 = *(const float4*)(red + (((l*4 + 2)*64 + d2)<<2));
    float4 s3 = *(const float4*)(red + (((l*4 + 3)*64 + d2)<<2));
    float4 o;
    o.x = s0.x+s1.x+s2.x+s3.x;
    o.y = s0.y+s1.y+s2.y+s3.y;
    o.z = s0.z+s1.z+s2.z+s3.z;
    o.w = s0.w+s1.w+s2.w+s3.w;
    *(float4*)&ws[OFF_AV + ((size_t)(bid*8 + l))*ND + d2*4] = o;
  }
}

// ---------------- kernel B1: combine + lat_ctx + {k2 | vW} ----------------
// grid = 256: block (b, half). half 0 -> K2 = lat@wlk; half 1 -> vW = lat@WVW.
__global__ __launch_bounds__(256) void kB1(const float* __restrict__ wlk,
                                           float* __restrict__ ws)
{
  int bid = blockIdx.x;
  int b = bid >> 1, half = bid & 1;
  int d = threadIdx.x;
  __shared__ float avnT[256][8];
  __shared__ float latT[256][8];

  float dent[8];
  #pragma unroll
  for (int l=0;l<8;l++){
    float s = 0.f;
    #pragma unroll
    for (int sp=0;sp<8;sp++) s += ws[OFF_DEN + (b*8+sp)*8 + l];
    dent[l] = s;
  }
  float av8[8];
  #pragma unroll
  for (int l=0;l<8;l++){
    float s = 0.f;
    #pragma unroll
    for (int sp=0;sp<8;sp++) s += ws[OFF_AV + ((size_t)((b*8+sp)*8 + l))*ND + d];
    av8[l] = s / dent[l];
  }
  *(float4*)&avnT[d][0] = make_float4(av8[0],av8[1],av8[2],av8[3]);
  *(float4*)&avnT[d][4] = make_float4(av8[4],av8[5],av8[6],av8[7]);
  __syncthreads();

  float lc[8];
  #pragma unroll
  for (int l=0;l<8;l++) lc[l] = 0.f;
  #pragma unroll 8
  for (int dd=0;dd<ND;dd++){
    float w = ws[OFF_WVO + dd*ND + d];
    float4 a0 = *(const float4*)&avnT[dd][0];
    float4 a1 = *(const float4*)&avnT[dd][4];
    lc[0]+=a0.x*w; lc[1]+=a0.y*w; lc[2]+=a0.z*w; lc[3]+=a0.w*w;
    lc[4]+=a1.x*w; lc[5]+=a1.y*w; lc[6]+=a1.z*w; lc[7]+=a1.w*w;
  }
  *(float4*)&latT[d][0] = make_float4(lc[0],lc[1],lc[2],lc[3]);
  *(float4*)&latT[d][4] = make_float4(lc[4],lc[5],lc[6],lc[7]);
  __syncthreads();

  const float* w3 = half ? (ws + OFF_WVW) : wlk;
  float o8[8];
  #pragma unroll
  for (int l=0;l<8;l++) o8[l] = 0.f;
  #pragma unroll 8
  for (int dd=0;dd<ND;dd++){
    float w = w3[dd*ND + d];
    float4 a0 = *(const float4*)&latT[dd][0];
    float4 a1 = *(const float4*)&latT[dd][4];
    o8[0]+=a0.x*w; o8[1]+=a0.y*w; o8[2]+=a0.z*w; o8[3]+=a0.w*w;
    o8[4]+=a1.x*w; o8[5]+=a1.y*w; o8[6]+=a1.z*w; o8[7]+=a1.w*w;
  }
  size_t obase = (half ? OFF_VW : OFF_K2) + (size_t)b*8*ND + d;
  #pragma unroll
  for (int l=0;l<8;l++) ws[obase + l*ND] = o8[l];
}

// ---------------- kernel B2: attn2 weights + gate + top2 + output ----------------
// grid = 128*6 ; block 256 ; p-tile = 28
__global__ __launch_bounds__(256) void kB2(const float* __restrict__ ws,
    const float* __restrict__ gw2, const float* __restrict__ gb2,
    const float* __restrict__ qe, float* __restrict__ out)
{
  int bid = blockIdx.x;
  int b = bid / 6, p0 = (bid % 6)*28;
  int tid = threadIdx.x;

  __shared__ float q2h[28][260];     // q2s tile, later h
  __shared__ float k2s[8][260];
  __shared__ float vws[8][260];
  __shared__ float wexp[28][8];
  __shared__ float lg[28][33];
  __shared__ float4 sel[28];

  // S0: stage (vectorized)
  #pragma unroll
  for (int i=0;i<7;i++){
    int idx = tid + i*256;
    int r = idx >> 6, c4 = idx & 63;
    *(float4*)&q2h[r][c4*4] = *(const float4*)&ws[OFF_Q2S + (p0+r)*ND + c4*4];
  }
  #pragma unroll
  for (int i=0;i<2;i++){
    int idx = tid + i*256;
    int l = idx >> 6, c4 = idx & 63;
    *(float4*)&k2s[l][c4*4] = *(const float4*)&ws[OFF_K2 + (b*8+l)*ND + c4*4];
    *(float4*)&vws[l][c4*4] = *(const float4*)&ws[OFF_VW + (b*8+l)*ND + c4*4];
  }
  __syncthreads();

  // S1: s2 dots + softmax over L=8
  {
    int pp = tid >> 3, l1 = tid & 7;
    if (pp < 28){
      float s2 = 0.f;
      #pragma unroll 8
      for (int i=0;i<64;i++){
        float4 qa = *(const float4*)&q2h[pp][4*i];
        float4 kb = *(const float4*)&k2s[l1][4*i];
        s2 += qa.x*kb.x + qa.y*kb.y + qa.z*kb.z + qa.w*kb.w;
      }
      float e2 = __expf(s2);
      float den = e2;
      den += __shfl_xor(den,1); den += __shfl_xor(den,2); den += __shfl_xor(den,4);
      wexp[pp][l1] = e2/den;
    }
  }
  __syncthreads();

  // S3: x[p][c=tid] = G0 + sum_l wexp[p][l]*vW[l][c] ; h = gelu(x) -> q2h
  {
    float vcol[8];
    #pragma unroll
    for (int l=0;l<8;l++) vcol[l] = vws[l][tid];
    #pragma unroll 4
    for (int p=0;p<28;p++){
      float4 w0 = *(const float4*)&wexp[p][0];
      float4 w1v = *(const float4*)&wexp[p][4];
      float x = ws[OFF_G0 + (p0+p)*ND + tid]
              + w0.x*vcol[0]+w0.y*vcol[1]+w0.z*vcol[2]+w0.w*vcol[3]
              + w1v.x*vcol[4]+w1v.y*vcol[5]+w1v.z*vcol[6]+w1v.w*vcol[7];
      q2h[p][tid] = 0.5f*x*(1.f+erff(x*0.70710678118654752f));
    }
  }
  __syncthreads();

  // S4: logits = h @ gw2 + b2
  {
    int e = tid & 31, pq = tid >> 5;
    if (pq < 7){
      float b2v = gb2[e];
      float a0=b2v, a1=b2v, a2=b2v, a3=b2v;
      for (int cc=0;cc<ND;cc+=4){
        float w20 = gw2[(cc+0)*NE + e];
        float w21 = gw2[(cc+1)*NE + e];
        float w22 = gw2[(cc+2)*NE + e];
        float w23 = gw2[(cc+3)*NE + e];
        float4 h0 = *(const float4*)&q2h[pq*4+0][cc];
        float4 h1 = *(const float4*)&q2h[pq*4+1][cc];
        float4 h2 = *(const float4*)&q2h[pq*4+2][cc];
        float4 h3 = *(const float4*)&q2h[pq*4+3][cc];
        a0 += h0.x*w20 + h0.y*w21 + h0.z*w22 + h0.w*w23;
        a1 += h1.x*w20 + h1.y*w21 + h1.z*w22 + h1.w*w23;
        a2 += h2.x*w20 + h2.y*w21 + h2.z*w22 + h2.w*w23;
        a3 += h3.x*w20 + h3.y*w21 + h3.z*w22 + h3.w*w23;
      }
      lg[pq*4+0][e] = a0;
      lg[pq*4+1][e] = a1;
      lg[pq*4+2][e] = a2;
      lg[pq*4+3][e] = a3;
    }
  }
  __syncthreads();

  // S5: top-2 + masked softmax weights
  if (tid < 28){
    float m1 = -1e30f, m2 = -1e30f;
    int e1 = 0, ee2 = 0;
    for (int e3=0;e3<NE;e3++){
      float v = lg[tid][e3];
      if (v > m1){ m2 = m1; ee2 = e1; m1 = v; e1 = e3; }
      else if (v > m2){ m2 = v; ee2 = e3; }
    }
    float z = __expf(m2 - m1);
    float inv = 1.f/(1.f+z);
    sel[tid] = make_float4(__int_as_float(e1), __int_as_float(ee2), inv, z*inv);
  }
  __syncthreads();

  // S6: output mix
  for (int p=0;p<28;p++){
    float4 s = sel[p];
    int e1 = __float_as_int(s.x), ee2 = __float_as_int(s.y);
    float q1v = qe[((size_t)e1*NP + (p0+p))*ND + tid];
    float q2v = qe[((size_t)ee2*NP + (p0+p))*ND + tid];
    out[((size_t)b*NP + (p0+p))*ND + tid] = s.z*q1v + s.w*q2v;
  }
}

extern "C" void kernel_launch(void* const* d_in, const int* in_sizes, int n_in,
                              void* d_out, int out_size, void* d_ws, size_t ws_size,
                              hipStream_t stream)
{
  const float* ctx  = (const float*)d_in[0];
  const float* qe   = (const float*)d_in[1];
  const float* qpos = (const float*)d_in[2];
  const float* lemb = (const float*)d_in[3];
  const float* lat  = (const float*)d_in[4];
  const float* wlq  = (const float*)d_in[5];
  const float* wck  = (const float*)d_in[6];
  const float* wcv  = (const float*)d_in[7];
  const float* wlo  = (const float*)d_in[8];
  const float* wsq  = (const float*)d_in[9];
  const float* wlk  = (const float*)d_in[10];
  const float* wlv  = (const float*)d_in[11];
  const float* wso  = (const float*)d_in[12];
  const float* gw1  = (const float*)d_in[13];
  const float* gb1  = (const float*)d_in[14];
  const float* gw2  = (const float*)d_in[15];
  const float* gb2  = (const float*)d_in[16];
  float* out = (float*)d_out;
  float* ws  = (float*)d_ws;

  pre1<<<512+NP+NL, 256, 0, stream>>>(lat, wlq, wcv, wlo, wso, gw1, gb1, qpos, lemb, wsq, ws);
  pre2<<<512, 256, 0, stream>>>(wck, wlv, ws);
  kA  <<<NB*8, 256, 0, stream>>>(ctx, ws);
  kB1 <<<NB*2, 256, 0, stream>>>(wlk, ws);
  kB2 <<<NB*6, 256, 0, stream>>>(ws, gw2, gb2, qe, out);
}